// Round 25
// baseline (290.998 us; speedup 1.0000x reference)
//
#include <hip/hip_runtime.h>
#include <cmath>

typedef __attribute__((ext_vector_type(4))) float f32x4;
typedef __attribute__((ext_vector_type(16))) float f32x16;
typedef __attribute__((ext_vector_type(8))) __bf16 bf16x8;
typedef __attribute__((ext_vector_type(8))) short s16x8;
typedef __attribute__((ext_vector_type(2))) unsigned int u32x2;

#define CB 4
#define CT 2048
#define CD 1024
#define CH 16
#define CDK 64
#define CBT 8192   // B*T
#define CBH 64     // B*H

#define GLOAD_LDS16(g, l)                                              \
  __builtin_amdgcn_global_load_lds(                                    \
      (const __attribute__((address_space(1))) unsigned int*)(g),      \
      (__attribute__((address_space(3))) unsigned int*)(l), 16, 0, 0)

__device__ __forceinline__ unsigned short f2bf(float f) {
  union { float f; unsigned u; } x; x.f = f;
  unsigned r = x.u + 0x7fffu + ((x.u >> 16) & 1u);
  return (unsigned short)(r >> 16);
}
__device__ __forceinline__ float bf2f(unsigned short b) {
  union { unsigned u; float f; } x; x.u = ((unsigned)b) << 16;
  return x.f;
}
__device__ __forceinline__ f32x4 mfma16(bf16x8 a, bf16x8 b, f32x4 c) {
  return __builtin_amdgcn_mfma_f32_16x16x32_bf16(a, b, c, 0, 0, 0);
}
__device__ __forceinline__ f32x16 mfma32(bf16x8 a, bf16x8 b, f32x16 c) {
  return __builtin_amdgcn_mfma_f32_32x32x16_bf16(a, b, c, 0, 0, 0);
}
__device__ __forceinline__ unsigned cvtpk(float lo, float hi) {
  unsigned r;
  asm("v_cvt_pk_bf16_f32 %0, %1, %2" : "=v"(r) : "v"(lo), "v"(hi));
  return r;
}

// ---------------- merged prep: convert x (blocks 0..8191) + transpose weights ----------------
__global__ void prep_inputs(const float* __restrict__ x,
                            unsigned short* __restrict__ xb,
                            const float* __restrict__ wqkv,
                            unsigned short* __restrict__ wqt,
                            const float* __restrict__ wout,
                            unsigned short* __restrict__ wot) {
  __shared__ float tile[32][33];
  const int b = blockIdx.x, tid = threadIdx.x;
  if (b < 8192) {
    const int i = (b * 256 + tid) * 4;
    float4 v = *(const float4*)(x + i);
    ushort4 o;
    o.x = f2bf(v.x); o.y = f2bf(v.y); o.z = f2bf(v.z); o.w = f2bf(v.w);
    *(ushort4*)(xb + i) = o;
    return;
  }
  const int bt = b - 8192;
  const int bx = bt & 127, rt = bt >> 7;
  const int xx = tid & 31, y0 = tid >> 5;  // (32, 8)
  const float* src;
  unsigned short* dst;
  int C, ct;
  if (bx < 96) { src = wqkv; dst = wqt; C = 3072; ct = bx; }
  else         { src = wout; dst = wot; C = 1024; ct = bx - 96; }
  const int R = 1024;
#pragma unroll
  for (int k = 0; k < 4; ++k) {
    int r = rt * 32 + y0 + k * 8;
    tile[y0 + k * 8][xx] = src[(size_t)r * C + ct * 32 + xx];
  }
  __syncthreads();
#pragma unroll
  for (int k = 0; k < 4; ++k) {
    int c = ct * 32 + y0 + k * 8;
    dst[(size_t)c * R + rt * 32 + xx] = f2bf(tile[xx][y0 + k * 8]);
  }
}

// ---------------- GEMM: C = A(bf16 [M][K]) * Bt(bf16 [N][K])^T + bias ----------------
// m97 structure (global_load_lds w16, T2 both-sides XOR swizzle), 2-D grid.
// MODE 0: per-wave-uniform qkv selector; RoPE/bias in-register, wave-private
//   LDS transpose -> fully coalesced 16B stores (q,k [t][d]; V^T [d][t]).
// MODE 1: fp32 out + bias
template <int MODE>
__global__ __launch_bounds__(256, 4) void gemm_bt(
    const unsigned short* __restrict__ A, const unsigned short* __restrict__ Bt,
    const float* __restrict__ bias, unsigned short* __restrict__ o0,
    unsigned short* __restrict__ o1, unsigned short* __restrict__ o2,
    float* __restrict__ fout, const float* __restrict__ cosT,
    const float* __restrict__ sinT, int M, int N, int K) {
  __shared__ __align__(16) unsigned short As[128 * 64];
  __shared__ __align__(16) unsigned short Bs[128 * 64];
  const int tid = threadIdx.x;
  const int lane = tid & 63, wid = tid >> 6;
  const int wr = wid >> 1, wc = wid & 1;
  const int m0 = blockIdx.x * 128, n0 = blockIdx.y * 128;
  const int l15 = lane & 15, l4 = lane >> 4;
  const int rx = l15 & 7;

  f32x4 acc[4][4];
#pragma unroll
  for (int i = 0; i < 4; ++i)
#pragma unroll
    for (int j = 0; j < 4; ++j) acc[i][j] = (f32x4){0.f, 0.f, 0.f, 0.f};

  const int srow = tid >> 3;
  const int scol = ((tid & 7) ^ (srow & 7)) * 8;
  const unsigned short* ag = A + (size_t)(m0 + srow) * K + scol;
  const unsigned short* bg = Bt + (size_t)(n0 + srow) * K + scol;
  unsigned short* asd = As + wid * 512;
  unsigned short* bsd = Bs + wid * 512;

  for (int k0 = 0; k0 < K; k0 += 64) {
#pragma unroll
    for (int p = 0; p < 4; ++p) {
      GLOAD_LDS16(ag + (size_t)(p * 32) * K + k0, asd + p * 2048);
      GLOAD_LDS16(bg + (size_t)(p * 32) * K + k0, bsd + p * 2048);
    }
    __syncthreads();
#pragma unroll
    for (int kk = 0; kk < 2; ++kk) {
      const int gsw = ((kk * 4 + l4) ^ rx) * 8;
      bf16x8 af[4], bfr[4];
#pragma unroll
      for (int i = 0; i < 4; ++i)
        af[i] = *(const bf16x8*)(&As[(wr * 64 + i * 16 + l15) * 64 + gsw]);
#pragma unroll
      for (int j = 0; j < 4; ++j)
        bfr[j] = *(const bf16x8*)(&Bs[(wc * 64 + j * 16 + l15) * 64 + gsw]);
#pragma unroll
      for (int i = 0; i < 4; ++i)
#pragma unroll
        for (int j = 0; j < 4; ++j)
          acc[i][j] = mfma16(af[i], bfr[j], acc[i][j]);
    }
    __syncthreads();
  }

  if (MODE == 1) {
#pragma unroll
    for (int i = 0; i < 4; ++i)
#pragma unroll
      for (int j = 0; j < 4; ++j) {
        const int row0 = m0 + wr * 64 + i * 16 + l4 * 4;
        const int col = n0 + wc * 64 + j * 16 + l15;
        const float bv = bias[col];
#pragma unroll
        for (int r = 0; r < 4; ++r)
          fout[(size_t)(row0 + r) * N + col] = acc[i][j][r] + bv;
      }
  } else {
    // wave-private LDS transpose epilogue (As/Bs free after final barrier)
    unsigned short* tr = (wid < 2) ? (As + wid * 4096) : (Bs + (wid - 2) * 4096);
    const int colbase = n0 + wc * 64;             // 64-aligned, sel-uniform
    const int h = colbase / 192;
    const int sel = (colbase % 192) >> 6;
    const int tokbase = m0 + wr * 64;             // within one batch b
    const int b = tokbase >> 11, t0 = tokbase & 2047;
    if (sel < 2) {
      const float qsc = (sel == 0) ? 0.18033688011112042592f : 1.0f;
      unsigned short* dstp = (sel == 0) ? o0 : o1;
#pragma unroll
      for (int i = 0; i < 4; ++i)
#pragma unroll
        for (int j = 0; j < 4; ++j) {
          const int d = j * 16 + l15;
          const int p = d >> 1;
          const float sgn = (d & 1) ? 1.0f : -1.0f;
          const float bv = bias[colbase + j * 16 + l15];
#pragma unroll
          for (int r = 0; r < 4; ++r) {
            const int rowl = i * 16 + l4 * 4 + r;
            const int t = t0 + rowl;
            const float v = acc[i][j][r] + bv;
            const float vp = __shfl_xor(v, 1);
            const float cs = cosT[t * 32 + p];
            const float sn = sinT[t * 32 + p];
            const float res = (v * cs + sgn * vp * sn) * qsc;
            tr[rowl * 64 + (((d >> 3) ^ (rowl & 7)) * 8) + (d & 7)] = f2bf(res);
          }
        }
#pragma unroll
      for (int s = 0; s < 8; ++s) {
        const int idx = s * 64 + lane;            // 512 granules: 64 rows x 8
        const int row = idx >> 3, g = idx & 7;
        s16x8 vrow = *(const s16x8*)(tr + row * 64 + ((g ^ (row & 7)) * 8));
        *(s16x8*)(dstp + ((size_t)((b * CH + h) * CT + t0 + row)) * CDK + g * 8) =
            vrow;
      }
    } else {
      // V^T: [d][t] tile, coalesced along t
#pragma unroll
      for (int i = 0; i < 4; ++i)
#pragma unroll
        for (int j = 0; j < 4; ++j) {
          const int d = j * 16 + l15;
          const float bv = bias[colbase + j * 16 + l15];
#pragma unroll
          for (int r = 0; r < 4; ++r) {
            const int tl = i * 16 + l4 * 4 + r;
            tr[d * 64 + (((tl >> 3) ^ (d & 7)) * 8) + (tl & 7)] =
                f2bf(acc[i][j][r] + bv);
          }
        }
#pragma unroll
      for (int s = 0; s < 8; ++s) {
        const int idx = s * 64 + lane;
        const int row = idx >> 3, g = idx & 7;    // row = local d
        s16x8 vrow = *(const s16x8*)(tr + row * 64 + ((g ^ (row & 7)) * 8));
        *(s16x8*)(&o2[((size_t)((b * CH + h) * CDK + row)) * CT + t0 + g * 8]) =
            vrow;
      }
    }
  }
}

// ---------------- flash attention v8: 3-buffer stage-after-barrier ----------
// 768 items (12 LPT-ordered per bh; long qb split into 2 KV chunks). Stage of
// tile j+2 issues AFTER barrier(j): barrier(j) proves all waves finished
// compute(j-1)'s reads of buf (j-1)%3 == (j+2)%3 -> mod-3 safe. 48KB LDS ->
// 3 blocks/CU (matches 768-block grid). vmcnt: outstanding = {j, j+1} -> 2/0.
__global__ __launch_bounds__(512, 6) void attn_fwd8(
    const unsigned short* __restrict__ qg, const unsigned short* __restrict__ kg,
    const unsigned short* __restrict__ vtg, unsigned short* __restrict__ ctx,
    unsigned short* __restrict__ opart, float* __restrict__ lpart) {
  __shared__ __align__(16) unsigned short smem[24576];  // 48KB
  unsigned short* Ks = smem;             // 3 bufs x 4096 shorts
  unsigned short* Vt = smem + 12288;     // 3 bufs x 4096 shorts
  const int tid = threadIdx.x, lane = tid & 63, w = tid >> 6;
  const int l31 = lane & 31, hi = lane >> 5;
  const int g8 = blockIdx.x & 7, r = blockIdx.x >> 3;
  const int bh = g8 + 8 * (r / 12);
  const int sub = r % 12;
  const int qb = (int)((0x014455266773ULL >> (sub * 4)) & 15);
  const int ch = (0x294 >> sub) & 1;
  const int split = (0x3DE >> sub) & 1;
  const int NJ = 4 * qb + 4;
  const int halfn = 2 * qb + 2;
  const int jbeg = ch * halfn;
  const int jend = split ? (jbeg + halfn) : NJ;

  const unsigned short* qp = qg + ((size_t)bh * CT + qb * 256) * CDK;
  const unsigned short* kp = kg + (size_t)bh * CT * CDK;
  const unsigned short* vp = vtg + (size_t)bh * CDK * CT;

  bf16x8 qf[4];
  {
    const unsigned short* qrow = qp + (size_t)(w * 32 + l31) * CDK + hi * 8;
#pragma unroll
    for (int ks = 0; ks < 4; ++ks) qf[ks] = *(const bf16x8*)(qrow + ks * 16);
  }
#pragma unroll
  for (int ks = 0; ks < 4; ++ks)
    asm volatile("" :: "v"(*(const f32x4*)&qf[ks]));

  const int lr = lane >> 3;
  const int srow = w * 8 + lr;
  const int gsw = ((lane & 7) ^ lr) * 8;
  const unsigned short* ksrc = kp + (size_t)srow * CDK + gsw;
  const unsigned short* vsrc = vp + (size_t)srow * CT + gsw;
  const int ldo = w * 512;

  const int njw = ((qb * 256 + w * 32 + 31) >> 6) + 1;
  const int qrow_g = qb * 256 + w * 32 + l31;

  auto STAGE = [&](int t, int buf) {
    GLOAD_LDS16(ksrc + (size_t)t * 64 * CDK, Ks + buf * 4096 + ldo);
    GLOAD_LDS16(vsrc + (size_t)t * 64, Vt + buf * 4096 + ldo);
  };

  f32x16 oacc[2];
#pragma unroll
  for (int nb = 0; nb < 2; ++nb)
#pragma unroll
    for (int r2 = 0; r2 < 16; ++r2) oacc[nb][r2] = 0.f;
  float lsum = 0.f;

  STAGE(jbeg, 0);
  STAGE(jbeg + 1, 1);

  int b0 = 0;  // buffer of tile j
  for (int j = jbeg; j < jend; ++j) {
    const int pend = jend - 1 - j;
    if (pend >= 1) asm volatile("s_waitcnt vmcnt(2)" ::: "memory");
    else           asm volatile("s_waitcnt vmcnt(0)" ::: "memory");
    __builtin_amdgcn_s_barrier();  // tile-j loads in LDS; buf (j+2)%3 now free
    int bp = b0 + 2; if (bp > 2) bp -= 3;
    if (j + 2 < jend) STAGE(j + 2, bp);

    if (j < njw) {
      const unsigned short* KB = Ks + b0 * 4096;
      const unsigned short* VB = Vt + b0 * 4096;

      f32x16 pacc[2];
      __builtin_amdgcn_s_setprio(1);
#pragma unroll
      for (int kb = 0; kb < 2; ++kb) {
#pragma unroll
        for (int r2 = 0; r2 < 16; ++r2) pacc[kb][r2] = 0.f;
#pragma unroll
        for (int ks = 0; ks < 4; ++ks) {
          const int row = kb * 32 + l31;
          bf16x8 kf = *(const bf16x8*)(KB + row * 64 + (((ks * 2 + hi) ^ (row & 7)) * 8));
          pacc[kb] = mfma32(kf, qf[ks], pacc[kb]);
        }
      }
      __builtin_amdgcn_s_setprio(0);

      if (j == njw - 1) {
        const int key0 = j * 64;
#pragma unroll
        for (int kb = 0; kb < 2; ++kb)
#pragma unroll
          for (int r2 = 0; r2 < 16; ++r2) {
            const int key = key0 + kb * 32 + (r2 & 3) + 8 * (r2 >> 2) + 4 * hi;
            if (key > qrow_g) pacc[kb][r2] = -1e30f;
          }
      }

#pragma unroll
      for (int kb = 0; kb < 2; ++kb)
#pragma unroll
        for (int r2 = 0; r2 < 16; ++r2)
          pacc[kb][r2] = __builtin_amdgcn_exp2f(pacc[kb][r2]);
      float rs;
      {
        float t[16];
#pragma unroll
        for (int r2 = 0; r2 < 16; ++r2) t[r2] = pacc[0][r2] + pacc[1][r2];
#pragma unroll
        for (int s = 8; s > 0; s >>= 1)
#pragma unroll
          for (int r2 = 0; r2 < s; ++r2) t[r2] += t[r2 + s];
        rs = t[0];
      }
      {
        unsigned ru = __float_as_uint(rs);
        u32x2 sw = __builtin_amdgcn_permlane32_swap(ru, ru, false, false);
        rs += __uint_as_float(hi ? sw[0] : sw[1]);
      }
      lsum += rs;

      bf16x8 pf[4];
#pragma unroll
      for (int kb = 0; kb < 2; ++kb)
#pragma unroll
        for (int half = 0; half < 2; ++half) {
          const int b0i = half * 8;
          unsigned c0 = cvtpk(pacc[kb][b0i + 0], pacc[kb][b0i + 1]);
          unsigned c1 = cvtpk(pacc[kb][b0i + 2], pacc[kb][b0i + 3]);
          unsigned c2 = cvtpk(pacc[kb][b0i + 4], pacc[kb][b0i + 5]);
          unsigned c3 = cvtpk(pacc[kb][b0i + 6], pacc[kb][b0i + 7]);
          u32x2 r02 = __builtin_amdgcn_permlane32_swap(c0, c2, false, false);
          u32x2 r13 = __builtin_amdgcn_permlane32_swap(c1, c3, false, false);
          union { unsigned u[4]; bf16x8 v; } fr;
          fr.u[0] = r02[0]; fr.u[1] = r13[0]; fr.u[2] = r02[1]; fr.u[3] = r13[1];
          pf[kb * 2 + half] = fr.v;
        }

      __builtin_amdgcn_s_setprio(1);
#pragma unroll
      for (int nb = 0; nb < 2; ++nb)
#pragma unroll
        for (int ks = 0; ks < 4; ++ks) {
          const int row = nb * 32 + l31;
          bf16x8 vf = *(const bf16x8*)(VB + row * 64 + (((ks * 2 + hi) ^ (row & 7)) * 8));
          oacc[nb] = mfma32(vf, pf[ks], oacc[nb]);
        }
      __builtin_amdgcn_s_setprio(0);
    }
    b0 = (b0 == 2) ? 0 : b0 + 1;
  }

  __syncthreads();

  // epilogue: bf16 LDS transpose; split writes partials (inv=1) to opart,
  // non-split writes normalized rows to ctx.
  unsigned short* tr = smem + w * 2048;
  const float inv = split ? 1.0f : (1.f / lsum);
#pragma unroll
  for (int nb = 0; nb < 2; ++nb)
#pragma unroll
    for (int rp = 0; rp < 8; ++rp) {
      const int r2 = rp * 2;
      unsigned pkd = cvtpk(oacc[nb][r2] * inv, oacc[nb][r2 + 1] * inv);
      const int d = nb * 32 + (r2 & 3) + 8 * (r2 >> 2) + 4 * hi;
      const int g = (d >> 3) ^ (l31 & 7);
      *(unsigned*)(tr + l31 * 64 + g * 8 + (d & 7)) = pkd;
    }
  if (!split) {
    const int b = bh >> 4, h = bh & 15;
#pragma unroll
    for (int s = 0; s < 4; ++s) {
      const int c = s * 64 + lane;
      const int qr = c >> 3, g = c & 7;
      s16x8 row = *(const s16x8*)(tr + qr * 64 + ((g ^ (qr & 7))) * 8);
      const int tok = qb * 256 + w * 32 + qr;
      *(s16x8*)(ctx + ((size_t)(b * CT + tok)) * CD + h * CDK + g * 8) = row;
    }
  } else {
    const int tokrel0 = qb * 256 + w * 32 - 1024;  // qb >= 4 here
    const size_t pbase = (size_t)(ch * 65536 + bh * 1024 + tokrel0);
#pragma unroll
    for (int s = 0; s < 4; ++s) {
      const int c = s * 64 + lane;
      const int qr = c >> 3, g = c & 7;
      s16x8 row = *(const s16x8*)(tr + qr * 64 + ((g ^ (qr & 7))) * 8);
      *(s16x8*)(opart + (pbase + qr) * 64 + g * 8) = row;
    }
    if (hi == 0) lpart[ch * 65536 + bh * 1024 + tokrel0 + l31] = lsum;
  }
}

// ---------------- combine bf16 chunk partials for tokens 1024..2047 ----------------
__global__ __launch_bounds__(256) void attn_reduce(
    const unsigned short* __restrict__ opart, const float* __restrict__ lpart,
    unsigned short* __restrict__ ctx) {
  const int gid = blockIdx.x * 256 + threadIdx.x;  // 524288 total
  const int row = gid >> 3, g = gid & 7;           // row: bh*1024 + tokrel
  s16x8 a8 = *(const s16x8*)(opart + (size_t)row * 64 + g * 8);
  s16x8 b8 = *(const s16x8*)(opart + ((size_t)65536 + row) * 64 + g * 8);
  const float inv = 1.f / (lpart[row] + lpart[65536 + row]);
  s16x8 o;
#pragma unroll
  for (int e = 0; e < 8; ++e)
    o[e] = (short)f2bf((bf2f((unsigned short)a8[e]) +
                        bf2f((unsigned short)b8[e])) * inv);
  const int bh = row >> 10, tokrel = row & 1023;
  const int b = bh >> 4, h = bh & 15;
  *(s16x8*)(ctx + ((size_t)(b * CT + 1024 + tokrel)) * CD + h * CDK + g * 8) = o;
}

extern "C" void kernel_launch(void* const* d_in, const int* in_sizes, int n_in,
                              void* d_out, int out_size, void* d_ws, size_t ws_size,
                              hipStream_t stream) {
  (void)in_sizes; (void)n_in; (void)out_size; (void)ws_size;
  const float* x     = (const float*)d_in[0];
  const float* W_qkv = (const float*)d_in[1];
  const float* b_qkv = (const float*)d_in[2];
  const float* W_out = (const float*)d_in[3];
  const float* b_out = (const float*)d_in[4];
  const float* cosT  = (const float*)d_in[5];
  const float* sinT  = (const float*)d_in[6];
  float* out = (float*)d_out;

  unsigned short* xb   = (unsigned short*)d_ws;            // [8192][1024]
  unsigned short* wqt  = xb + (size_t)CBT * CD;            // [3072][1024]
  unsigned short* wot  = wqt + (size_t)3 * CD * CD;        // [1024][1024]
  unsigned short* qbuf = wot + (size_t)CD * CD;            // [64][2048][64]
  unsigned short* kbuf = qbuf + (size_t)CBH * CT * CDK;    // [64][2048][64]
  unsigned short* vbuf = kbuf + (size_t)CBH * CT * CDK;    // [64][64][2048] (V^T)
  unsigned short* ctx  = vbuf + (size_t)CBH * CT * CDK;    // [8192][1024]
  unsigned short* opart = ctx + (size_t)CBT * CD;          // [2][65536][64] bf16
  float* lpart = (float*)(opart + (size_t)2 * 65536 * 64); // [2][65536] f32

  prep_inputs<<<dim3(8192 + 4096), 256, 0, stream>>>(x, xb, W_qkv, wqt,
                                                     W_out, wot);
  gemm_bt<0><<<dim3(CBT / 128, 3 * CD / 128), 256, 0, stream>>>(
      xb, wqt, b_qkv, qbuf, kbuf, vbuf, nullptr, cosT, sinT, CBT, 3 * CD, CD);
  attn_fwd8<<<dim3(768), 512, 0, stream>>>(qbuf, kbuf, vbuf, ctx, opart, lpart);
  attn_reduce<<<dim3(2048), 256, 0, stream>>>(opart, lpart, ctx);
  gemm_bt<1><<<dim3(CBT / 128, CD / 128), 256, 0, stream>>>(
      ctx, wot, b_out, nullptr, nullptr, nullptr, out, nullptr, nullptr,
      CBT, CD, CD);
}

// Round 26
// 155.283 us; speedup vs baseline: 1.8740x; 1.8740x over previous
//
#include <hip/hip_runtime.h>
#include <cmath>

typedef __attribute__((ext_vector_type(4))) float f32x4;
typedef __attribute__((ext_vector_type(16))) float f32x16;
typedef __attribute__((ext_vector_type(8))) __bf16 bf16x8;
typedef __attribute__((ext_vector_type(8))) short s16x8;
typedef __attribute__((ext_vector_type(2))) unsigned int u32x2;

#define CB 4
#define CT 2048
#define CD 1024
#define CH 16
#define CDK 64
#define CBT 8192   // B*T
#define CBH 64     // B*H

#define GLOAD_LDS16(g, l)                                              \
  __builtin_amdgcn_global_load_lds(                                    \
      (const __attribute__((address_space(1))) unsigned int*)(g),      \
      (__attribute__((address_space(3))) unsigned int*)(l), 16, 0, 0)

__device__ __forceinline__ unsigned short f2bf(float f) {
  union { float f; unsigned u; } x; x.f = f;
  unsigned r = x.u + 0x7fffu + ((x.u >> 16) & 1u);
  return (unsigned short)(r >> 16);
}
__device__ __forceinline__ float bf2f(unsigned short b) {
  union { unsigned u; float f; } x; x.u = ((unsigned)b) << 16;
  return x.f;
}
__device__ __forceinline__ f32x4 mfma16(bf16x8 a, bf16x8 b, f32x4 c) {
  return __builtin_amdgcn_mfma_f32_16x16x32_bf16(a, b, c, 0, 0, 0);
}
__device__ __forceinline__ f32x16 mfma32(bf16x8 a, bf16x8 b, f32x16 c) {
  return __builtin_amdgcn_mfma_f32_32x32x16_bf16(a, b, c, 0, 0, 0);
}
__device__ __forceinline__ unsigned cvtpk(float lo, float hi) {
  unsigned r;
  asm("v_cvt_pk_bf16_f32 %0, %1, %2" : "=v"(r) : "v"(lo), "v"(hi));
  return r;
}

// ---------------- merged prep: convert x (blocks 0..8191) + transpose weights ----------------
__global__ void prep_inputs(const float* __restrict__ x,
                            unsigned short* __restrict__ xb,
                            const float* __restrict__ wqkv,
                            unsigned short* __restrict__ wqt,
                            const float* __restrict__ wout,
                            unsigned short* __restrict__ wot) {
  __shared__ float tile[32][33];
  const int b = blockIdx.x, tid = threadIdx.x;
  if (b < 8192) {
    const int i = (b * 256 + tid) * 4;
    float4 v = *(const float4*)(x + i);
    ushort4 o;
    o.x = f2bf(v.x); o.y = f2bf(v.y); o.z = f2bf(v.z); o.w = f2bf(v.w);
    *(ushort4*)(xb + i) = o;
    return;
  }
  const int bt = b - 8192;
  const int bx = bt & 127, rt = bt >> 7;
  const int xx = tid & 31, y0 = tid >> 5;  // (32, 8)
  const float* src;
  unsigned short* dst;
  int C, ct;
  if (bx < 96) { src = wqkv; dst = wqt; C = 3072; ct = bx; }
  else         { src = wout; dst = wot; C = 1024; ct = bx - 96; }
  const int R = 1024;
#pragma unroll
  for (int k = 0; k < 4; ++k) {
    int r = rt * 32 + y0 + k * 8;
    tile[y0 + k * 8][xx] = src[(size_t)r * C + ct * 32 + xx];
  }
  __syncthreads();
#pragma unroll
  for (int k = 0; k < 4; ++k) {
    int c = ct * 32 + y0 + k * 8;
    dst[(size_t)c * R + rt * 32 + xx] = f2bf(tile[xx][y0 + k * 8]);
  }
}

// ---------------- GEMM: C = A(bf16 [M][K]) * Bt(bf16 [N][K])^T + bias ----------------
// m97 structure (global_load_lds w16, T2 both-sides XOR swizzle), 2-D grid.
// MODE 0: per-wave-uniform qkv selector; RoPE/bias in-register, wave-private
//   LDS transpose -> fully coalesced 16B stores (q,k [t][d]; V^T [d][t]).
// MODE 1: fp32 out + bias
template <int MODE>
__global__ __launch_bounds__(256, 4) void gemm_bt(
    const unsigned short* __restrict__ A, const unsigned short* __restrict__ Bt,
    const float* __restrict__ bias, unsigned short* __restrict__ o0,
    unsigned short* __restrict__ o1, unsigned short* __restrict__ o2,
    float* __restrict__ fout, const float* __restrict__ cosT,
    const float* __restrict__ sinT, int M, int N, int K) {
  __shared__ __align__(16) unsigned short As[128 * 64];
  __shared__ __align__(16) unsigned short Bs[128 * 64];
  const int tid = threadIdx.x;
  const int lane = tid & 63, wid = tid >> 6;
  const int wr = wid >> 1, wc = wid & 1;
  const int m0 = blockIdx.x * 128, n0 = blockIdx.y * 128;
  const int l15 = lane & 15, l4 = lane >> 4;
  const int rx = l15 & 7;

  f32x4 acc[4][4];
#pragma unroll
  for (int i = 0; i < 4; ++i)
#pragma unroll
    for (int j = 0; j < 4; ++j) acc[i][j] = (f32x4){0.f, 0.f, 0.f, 0.f};

  const int srow = tid >> 3;
  const int scol = ((tid & 7) ^ (srow & 7)) * 8;
  const unsigned short* ag = A + (size_t)(m0 + srow) * K + scol;
  const unsigned short* bg = Bt + (size_t)(n0 + srow) * K + scol;
  unsigned short* asd = As + wid * 512;
  unsigned short* bsd = Bs + wid * 512;

  for (int k0 = 0; k0 < K; k0 += 64) {
#pragma unroll
    for (int p = 0; p < 4; ++p) {
      GLOAD_LDS16(ag + (size_t)(p * 32) * K + k0, asd + p * 2048);
      GLOAD_LDS16(bg + (size_t)(p * 32) * K + k0, bsd + p * 2048);
    }
    __syncthreads();
#pragma unroll
    for (int kk = 0; kk < 2; ++kk) {
      const int gsw = ((kk * 4 + l4) ^ rx) * 8;
      bf16x8 af[4], bfr[4];
#pragma unroll
      for (int i = 0; i < 4; ++i)
        af[i] = *(const bf16x8*)(&As[(wr * 64 + i * 16 + l15) * 64 + gsw]);
#pragma unroll
      for (int j = 0; j < 4; ++j)
        bfr[j] = *(const bf16x8*)(&Bs[(wc * 64 + j * 16 + l15) * 64 + gsw]);
#pragma unroll
      for (int i = 0; i < 4; ++i)
#pragma unroll
        for (int j = 0; j < 4; ++j)
          acc[i][j] = mfma16(af[i], bfr[j], acc[i][j]);
    }
    __syncthreads();
  }

  if (MODE == 1) {
#pragma unroll
    for (int i = 0; i < 4; ++i)
#pragma unroll
      for (int j = 0; j < 4; ++j) {
        const int row0 = m0 + wr * 64 + i * 16 + l4 * 4;
        const int col = n0 + wc * 64 + j * 16 + l15;
        const float bv = bias[col];
#pragma unroll
        for (int r = 0; r < 4; ++r)
          fout[(size_t)(row0 + r) * N + col] = acc[i][j][r] + bv;
      }
  } else {
    // wave-private LDS transpose epilogue (As/Bs free after final barrier)
    unsigned short* tr = (wid < 2) ? (As + wid * 4096) : (Bs + (wid - 2) * 4096);
    const int colbase = n0 + wc * 64;             // 64-aligned, sel-uniform
    const int h = colbase / 192;
    const int sel = (colbase % 192) >> 6;
    const int tokbase = m0 + wr * 64;             // within one batch b
    const int b = tokbase >> 11, t0 = tokbase & 2047;
    if (sel < 2) {
      const float qsc = (sel == 0) ? 0.18033688011112042592f : 1.0f;
      unsigned short* dstp = (sel == 0) ? o0 : o1;
#pragma unroll
      for (int i = 0; i < 4; ++i)
#pragma unroll
        for (int j = 0; j < 4; ++j) {
          const int d = j * 16 + l15;
          const int p = d >> 1;
          const float sgn = (d & 1) ? 1.0f : -1.0f;
          const float bv = bias[colbase + j * 16 + l15];
#pragma unroll
          for (int r = 0; r < 4; ++r) {
            const int rowl = i * 16 + l4 * 4 + r;
            const int t = t0 + rowl;
            const float v = acc[i][j][r] + bv;
            const float vp = __shfl_xor(v, 1);
            const float cs = cosT[t * 32 + p];
            const float sn = sinT[t * 32 + p];
            const float res = (v * cs + sgn * vp * sn) * qsc;
            tr[rowl * 64 + (((d >> 3) ^ (rowl & 7)) * 8) + (d & 7)] = f2bf(res);
          }
        }
#pragma unroll
      for (int s = 0; s < 8; ++s) {
        const int idx = s * 64 + lane;            // 512 granules: 64 rows x 8
        const int row = idx >> 3, g = idx & 7;
        s16x8 vrow = *(const s16x8*)(tr + row * 64 + ((g ^ (row & 7)) * 8));
        *(s16x8*)(dstp + ((size_t)((b * CH + h) * CT + t0 + row)) * CDK + g * 8) =
            vrow;
      }
    } else {
      // V^T: [d][t] tile, coalesced along t
#pragma unroll
      for (int i = 0; i < 4; ++i)
#pragma unroll
        for (int j = 0; j < 4; ++j) {
          const int d = j * 16 + l15;
          const float bv = bias[colbase + j * 16 + l15];
#pragma unroll
          for (int r = 0; r < 4; ++r) {
            const int tl = i * 16 + l4 * 4 + r;
            tr[d * 64 + (((tl >> 3) ^ (d & 7)) * 8) + (tl & 7)] =
                f2bf(acc[i][j][r] + bv);
          }
        }
#pragma unroll
      for (int s = 0; s < 8; ++s) {
        const int idx = s * 64 + lane;
        const int row = idx >> 3, g = idx & 7;    // row = local d
        s16x8 vrow = *(const s16x8*)(tr + row * 64 + ((g ^ (row & 7)) * 8));
        *(s16x8*)(&o2[((size_t)((b * CH + h) * CDK + row)) * CT + t0 + g * 8]) =
            vrow;
      }
    }
  }
}

// ---------------- flash attention v7: KV-split work items ----------------
// 768 items: per bh, 12 LPT-ordered items (long qb split into 2 KV chunks).
// Max-free softmax => chunk partials (O,l) are pure sums; partials stored
// bf16 (one extra rounding, << threshold). 4-buffer one-barrier pipeline,
// counted vmcnt, T12 P-frags, setprio.
__global__ __launch_bounds__(512, 4) void attn_fwd7(
    const unsigned short* __restrict__ qg, const unsigned short* __restrict__ kg,
    const unsigned short* __restrict__ vtg, unsigned short* __restrict__ ctx,
    unsigned short* __restrict__ opart, float* __restrict__ lpart) {
  __shared__ __align__(16) unsigned short smem[32768];  // 64KB
  unsigned short* Ks = smem;
  unsigned short* Vt = smem + 16384;
  const int tid = threadIdx.x, lane = tid & 63, w = tid >> 6;
  const int l31 = lane & 31, hi = lane >> 5;
  const int g8 = blockIdx.x & 7, r = blockIdx.x >> 3;
  const int bh = g8 + 8 * (r / 12);
  const int sub = r % 12;
  const int qb = (int)((0x014455266773ULL >> (sub * 4)) & 15);
  const int ch = (0x294 >> sub) & 1;
  const int split = (0x3DE >> sub) & 1;
  const int NJ = 4 * qb + 4;
  const int halfn = 2 * qb + 2;
  const int jbeg = ch * halfn;
  const int jend = split ? (jbeg + halfn) : NJ;

  const unsigned short* qp = qg + ((size_t)bh * CT + qb * 256) * CDK;
  const unsigned short* kp = kg + (size_t)bh * CT * CDK;
  const unsigned short* vp = vtg + (size_t)bh * CDK * CT;

  bf16x8 qf[4];
  {
    const unsigned short* qrow = qp + (size_t)(w * 32 + l31) * CDK + hi * 8;
#pragma unroll
    for (int ks = 0; ks < 4; ++ks) qf[ks] = *(const bf16x8*)(qrow + ks * 16);
  }
#pragma unroll
  for (int ks = 0; ks < 4; ++ks)
    asm volatile("" :: "v"(*(const f32x4*)&qf[ks]));

  const int lr = lane >> 3;
  const int srow = w * 8 + lr;
  const int gsw = ((lane & 7) ^ lr) * 8;
  const unsigned short* ksrc = kp + (size_t)srow * CDK + gsw;
  const unsigned short* vsrc = vp + (size_t)srow * CT + gsw;
  const int ldo = w * 512;

  const int njw = ((qb * 256 + w * 32 + 31) >> 6) + 1;
  const int qrow_g = qb * 256 + w * 32 + l31;

  auto STAGE = [&](int t) {
    const int buf = t & 3;
    GLOAD_LDS16(ksrc + (size_t)t * 64 * CDK, Ks + buf * 4096 + ldo);
    GLOAD_LDS16(vsrc + (size_t)t * 64, Vt + buf * 4096 + ldo);
  };

  f32x16 oacc[2];
#pragma unroll
  for (int nb = 0; nb < 2; ++nb)
#pragma unroll
    for (int r2 = 0; r2 < 16; ++r2) oacc[nb][r2] = 0.f;
  float lsum = 0.f;

  STAGE(jbeg);
  STAGE(jbeg + 1);

  for (int j = jbeg; j < jend; ++j) {
    if (j + 2 < jend) STAGE(j + 2);
    const int pend = jend - 1 - j;
    if (pend >= 2)      asm volatile("s_waitcnt vmcnt(4)" ::: "memory");
    else if (pend == 1) asm volatile("s_waitcnt vmcnt(2)" ::: "memory");
    else                asm volatile("s_waitcnt vmcnt(0)" ::: "memory");
    __builtin_amdgcn_s_barrier();

    if (j < njw) {
      const unsigned short* KB = Ks + (j & 3) * 4096;
      const unsigned short* VB = Vt + (j & 3) * 4096;

      f32x16 pacc[2];
      __builtin_amdgcn_s_setprio(1);
#pragma unroll
      for (int kb = 0; kb < 2; ++kb) {
#pragma unroll
        for (int r2 = 0; r2 < 16; ++r2) pacc[kb][r2] = 0.f;
#pragma unroll
        for (int ks = 0; ks < 4; ++ks) {
          const int row = kb * 32 + l31;
          bf16x8 kf = *(const bf16x8*)(KB + row * 64 + (((ks * 2 + hi) ^ (row & 7)) * 8));
          pacc[kb] = mfma32(kf, qf[ks], pacc[kb]);
        }
      }
      __builtin_amdgcn_s_setprio(0);

      if (j == njw - 1) {
        const int key0 = j * 64;
#pragma unroll
        for (int kb = 0; kb < 2; ++kb)
#pragma unroll
          for (int r2 = 0; r2 < 16; ++r2) {
            const int key = key0 + kb * 32 + (r2 & 3) + 8 * (r2 >> 2) + 4 * hi;
            if (key > qrow_g) pacc[kb][r2] = -1e30f;
          }
      }

#pragma unroll
      for (int kb = 0; kb < 2; ++kb)
#pragma unroll
        for (int r2 = 0; r2 < 16; ++r2)
          pacc[kb][r2] = __builtin_amdgcn_exp2f(pacc[kb][r2]);
      float rs;
      {
        float t[16];
#pragma unroll
        for (int r2 = 0; r2 < 16; ++r2) t[r2] = pacc[0][r2] + pacc[1][r2];
#pragma unroll
        for (int s = 8; s > 0; s >>= 1)
#pragma unroll
          for (int r2 = 0; r2 < s; ++r2) t[r2] += t[r2 + s];
        rs = t[0];
      }
      {
        unsigned ru = __float_as_uint(rs);
        u32x2 sw = __builtin_amdgcn_permlane32_swap(ru, ru, false, false);
        rs += __uint_as_float(hi ? sw[0] : sw[1]);
      }
      lsum += rs;

      bf16x8 pf[4];
#pragma unroll
      for (int kb = 0; kb < 2; ++kb)
#pragma unroll
        for (int half = 0; half < 2; ++half) {
          const int b0i = half * 8;
          unsigned c0 = cvtpk(pacc[kb][b0i + 0], pacc[kb][b0i + 1]);
          unsigned c1 = cvtpk(pacc[kb][b0i + 2], pacc[kb][b0i + 3]);
          unsigned c2 = cvtpk(pacc[kb][b0i + 4], pacc[kb][b0i + 5]);
          unsigned c3 = cvtpk(pacc[kb][b0i + 6], pacc[kb][b0i + 7]);
          u32x2 r02 = __builtin_amdgcn_permlane32_swap(c0, c2, false, false);
          u32x2 r13 = __builtin_amdgcn_permlane32_swap(c1, c3, false, false);
          union { unsigned u[4]; bf16x8 v; } fr;
          fr.u[0] = r02[0]; fr.u[1] = r13[0]; fr.u[2] = r02[1]; fr.u[3] = r13[1];
          pf[kb * 2 + half] = fr.v;
        }

      __builtin_amdgcn_s_setprio(1);
#pragma unroll
      for (int nb = 0; nb < 2; ++nb)
#pragma unroll
        for (int ks = 0; ks < 4; ++ks) {
          const int row = nb * 32 + l31;
          bf16x8 vf = *(const bf16x8*)(VB + row * 64 + (((ks * 2 + hi) ^ (row & 7)) * 8));
          oacc[nb] = mfma32(vf, pf[ks], oacc[nb]);
        }
      __builtin_amdgcn_s_setprio(0);
    }
  }

  __syncthreads();

  // epilogue: bf16 LDS transpose; split writes partials (inv=1) to opart,
  // non-split writes normalized rows to ctx.
  unsigned short* tr = smem + w * 2048;
  const float inv = split ? 1.0f : (1.f / lsum);
#pragma unroll
  for (int nb = 0; nb < 2; ++nb)
#pragma unroll
    for (int rp = 0; rp < 8; ++rp) {
      const int r2 = rp * 2;
      unsigned pkd = cvtpk(oacc[nb][r2] * inv, oacc[nb][r2 + 1] * inv);
      const int d = nb * 32 + (r2 & 3) + 8 * (r2 >> 2) + 4 * hi;
      const int g = (d >> 3) ^ (l31 & 7);
      *(unsigned*)(tr + l31 * 64 + g * 8 + (d & 7)) = pkd;
    }
  if (!split) {
    const int b = bh >> 4, h = bh & 15;
#pragma unroll
    for (int s = 0; s < 4; ++s) {
      const int c = s * 64 + lane;
      const int qr = c >> 3, g = c & 7;
      s16x8 row = *(const s16x8*)(tr + qr * 64 + ((g ^ (qr & 7))) * 8);
      const int tok = qb * 256 + w * 32 + qr;
      *(s16x8*)(ctx + ((size_t)(b * CT + tok)) * CD + h * CDK + g * 8) = row;
    }
  } else {
    const int tokrel0 = qb * 256 + w * 32 - 1024;  // qb >= 4 here
    const size_t pbase = (size_t)(ch * 65536 + bh * 1024 + tokrel0);
#pragma unroll
    for (int s = 0; s < 4; ++s) {
      const int c = s * 64 + lane;
      const int qr = c >> 3, g = c & 7;
      s16x8 row = *(const s16x8*)(tr + qr * 64 + ((g ^ (qr & 7))) * 8);
      *(s16x8*)(opart + (pbase + qr) * 64 + g * 8) = row;
    }
    if (hi == 0) lpart[ch * 65536 + bh * 1024 + tokrel0 + l31] = lsum;
  }
}

// ---------------- combine bf16 chunk partials for tokens 1024..2047 ----------------
__global__ __launch_bounds__(256) void attn_reduce(
    const unsigned short* __restrict__ opart, const float* __restrict__ lpart,
    unsigned short* __restrict__ ctx) {
  const int gid = blockIdx.x * 256 + threadIdx.x;  // 524288 total
  const int row = gid >> 3, g = gid & 7;           // row: bh*1024 + tokrel
  s16x8 a8 = *(const s16x8*)(opart + (size_t)row * 64 + g * 8);
  s16x8 b8 = *(const s16x8*)(opart + ((size_t)65536 + row) * 64 + g * 8);
  const float inv = 1.f / (lpart[row] + lpart[65536 + row]);
  s16x8 o;
#pragma unroll
  for (int e = 0; e < 8; ++e)
    o[e] = (short)f2bf((bf2f((unsigned short)a8[e]) +
                        bf2f((unsigned short)b8[e])) * inv);
  const int bh = row >> 10, tokrel = row & 1023;
  const int b = bh >> 4, h = bh & 15;
  *(s16x8*)(ctx + ((size_t)(b * CT + 1024 + tokrel)) * CD + h * CDK + g * 8) = o;
}

extern "C" void kernel_launch(void* const* d_in, const int* in_sizes, int n_in,
                              void* d_out, int out_size, void* d_ws, size_t ws_size,
                              hipStream_t stream) {
  (void)in_sizes; (void)n_in; (void)out_size; (void)ws_size;
  const float* x     = (const float*)d_in[0];
  const float* W_qkv = (const float*)d_in[1];
  const float* b_qkv = (const float*)d_in[2];
  const float* W_out = (const float*)d_in[3];
  const float* b_out = (const float*)d_in[4];
  const float* cosT  = (const float*)d_in[5];
  const float* sinT  = (const float*)d_in[6];
  float* out = (float*)d_out;

  unsigned short* xb   = (unsigned short*)d_ws;            // [8192][1024]
  unsigned short* wqt  = xb + (size_t)CBT * CD;            // [3072][1024]
  unsigned short* wot  = wqt + (size_t)3 * CD * CD;        // [1024][1024]
  unsigned short* qbuf = wot + (size_t)CD * CD;            // [64][2048][64]
  unsigned short* kbuf = qbuf + (size_t)CBH * CT * CDK;    // [64][2048][64]
  unsigned short* vbuf = kbuf + (size_t)CBH * CT * CDK;    // [64][64][2048] (V^T)
  unsigned short* ctx  = vbuf + (size_t)CBH * CT * CDK;    // [8192][1024]
  unsigned short* opart = ctx + (size_t)CBT * CD;          // [2][65536][64] bf16
  float* lpart = (float*)(opart + (size_t)2 * 65536 * 64); // [2][65536] f32

  prep_inputs<<<dim3(8192 + 4096), 256, 0, stream>>>(x, xb, W_qkv, wqt,
                                                     W_out, wot);
  gemm_bt<0><<<dim3(CBT / 128, 3 * CD / 128), 256, 0, stream>>>(
      xb, wqt, b_qkv, qbuf, kbuf, vbuf, nullptr, cosT, sinT, CBT, 3 * CD, CD);
  attn_fwd7<<<dim3(768), 512, 0, stream>>>(qbuf, kbuf, vbuf, ctx, opart, lpart);
  attn_reduce<<<dim3(2048), 256, 0, stream>>>(opart, lpart, ctx);
  gemm_bt<1><<<dim3(CBT / 128, CD / 128), 256, 0, stream>>>(
      ctx, wot, b_out, nullptr, nullptr, nullptr, out, nullptr, nullptr,
      CBT, CD, CD);
}